// Round 1
// baseline (274.664 us; speedup 1.0000x reference)
//
#include <hip/hip_runtime.h>
#include <cstdint>

// Problem constants (match reference)
#define TOK 2048
#define HD  1024
#define ID  768
#define NE  32

typedef unsigned short u16t;
typedef unsigned int   u32t;
typedef __bf16 bf16x8 __attribute__((ext_vector_type(8)));
typedef float  f32x4  __attribute__((ext_vector_type(4)));
typedef u16t   u16x8  __attribute__((ext_vector_type(8)));
typedef u16t   u16x4  __attribute__((ext_vector_type(4)));
typedef float  fvec4  __attribute__((ext_vector_type(4)));

// f32 -> bf16 round-to-nearest-even (inputs are well-behaved, no NaN path)
__device__ __forceinline__ u16t f2b(float f) {
  u32t u = __float_as_uint(f);
  u32t r = u + 0x7fffu + ((u >> 16) & 1u);
  return (u16t)(r >> 16);
}

// LDS granule swizzle: granule = 8 bf16 (16B). Layout [row][4 granules of k].
// XOR k-chunk with (row>>2)&3 so 16 consecutive rows at fixed kc spread over
// 8 bank-groups -> minimal (2-way) conflict for ds_read_b128.
// Used by BOTH write and read so consistency is guaranteed by construction.
__device__ __forceinline__ int swz(int row, int kc) {
  return (row * 4 + (kc ^ ((row >> 2) & 3))) * 8;   // index in u16 units
}

// ---------------------------------------------------------------- k_cvt ----
__global__ void k_cvt(const float* __restrict__ x, u16t* __restrict__ xb) {
  int i = (blockIdx.x * 256 + threadIdx.x) * 4;
  fvec4 v = *(const fvec4*)(x + i);
  u16x4 o = { f2b(v[0]), f2b(v[1]), f2b(v[2]), f2b(v[3]) };
  *(u16x4*)(xb + i) = o;
}

// -------------------------------------------------------------- k_router ---
// 1 wave per token. f32 logits, sigmoid scores, top-4 of (score+bias) with
// lowest-index tie-break (matches lax.top_k), renormalized sigmoid weights.
__global__ void k_router(const float* __restrict__ x, const float* __restrict__ gw,
                         const float* __restrict__ eb,
                         int* __restrict__ topk_ids, float* __restrict__ topk_w,
                         int* __restrict__ counts) {
  int lane = threadIdx.x & 63;
  int t = blockIdx.x * 4 + (threadIdx.x >> 6);
  const float* xt = x + (size_t)t * HD;
  float myscore = 0.f;
  for (int e = 0; e < NE; ++e) {
    const float* ge = gw + (size_t)e * HD;
    float s = 0.f;
#pragma unroll
    for (int i = 0; i < HD / 64; ++i) s = fmaf(xt[lane + i * 64], ge[lane + i * 64], s);
#pragma unroll
    for (int off = 32; off; off >>= 1) s += __shfl_xor(s, off);
    if (lane == e) myscore = s;
  }
  float sig = 1.f / (1.f + expf(-myscore));
  float biased = (lane < NE) ? (sig + eb[lane]) : -3.0e38f;
  float wsum = 0.f;
  int ids[4]; float wsv[4];
#pragma unroll
  for (int k = 0; k < 4; ++k) {
    float v = biased; int idx = lane;
#pragma unroll
    for (int off = 32; off; off >>= 1) {
      float ov = __shfl_xor(v, off);
      int   oi = __shfl_xor(idx, off);
      if (ov > v || (ov == v && oi < idx)) { v = ov; idx = oi; }
    }
    ids[k] = idx;
    float sc = __shfl(sig, idx);   // uncorrected sigmoid score is the weight
    wsv[k] = sc; wsum += sc;
    if (lane == idx) biased = -3.0e38f;
  }
  float inv = 1.f / wsum;
#pragma unroll
  for (int k = 0; k < 4; ++k) {
    if (lane == k) {
      topk_ids[t * 4 + k] = ids[k];
      topk_w[t * 4 + k]  = wsv[k] * inv;
      atomicAdd(&counts[ids[k]], 1);
    }
  }
}

// -------------------------------------------------------------- k_bucket ---
// Single block: scan counts -> offsets, scatter pairs into expert buckets.
// Scatter order is non-deterministic but every downstream value is a pure
// function of the pair -> output deterministic.
__global__ void k_bucket(const int* __restrict__ topk_ids, const float* __restrict__ topk_w,
                         const int* __restrict__ counts, int* __restrict__ offsets,
                         int* __restrict__ pairTok, float* __restrict__ pairW,
                         int* __restrict__ invp) {
  __shared__ int soff[NE + 1];
  __shared__ int scur[NE];
  int tid = threadIdx.x;
  if (tid == 0) {
    int acc = 0;
    for (int e = 0; e < NE; ++e) { soff[e] = acc; acc += counts[e]; }
    soff[NE] = acc;
  }
  if (tid < NE) scur[tid] = 0;
  __syncthreads();
  if (tid <= NE) offsets[tid] = soff[tid];
  for (int p = tid; p < TOK * 4; p += 256) {
    int e = topk_ids[p];
    int pos = soff[e] + atomicAdd(&scur[e], 1);
    pairTok[pos] = p;          // p = t*4+k
    pairW[pos]   = topk_w[p];
    invp[p]      = pos;
  }
}

// --------------------------------------------------------------- k_gemm1 ---
// Per (expert, 64-wide col tile of I): loop 256-row tiles of this expert's
// pair bucket. g = X@w1, u = X@w3 via bf16 MFMA, epilogue silu(g)*u*w -> A.
__launch_bounds__(256, 2)
__global__ void k_gemm1(const u16t* __restrict__ xb, const float* __restrict__ w1,
                        const float* __restrict__ w3,
                        const int* __restrict__ counts, const int* __restrict__ offsets,
                        const int* __restrict__ pairTok, const float* __restrict__ pairW,
                        u16t* __restrict__ A) {
  const int e = blockIdx.y;
  const int colbase = blockIdx.x * 64;
  const int count = counts[e];
  const int base  = offsets[e];
  const int tid = threadIdx.x, lane = tid & 63, wv = tid >> 6;

  __shared__ __align__(16) u16t Xs[256 * 32];     // 16 KB, swizzled [row][k]
  __shared__ __align__(16) u16t Ws2[2][64 * 32];  // w1/w3 tiles, [col][k] swizzled
  __shared__ float pw[256];
  __shared__ int   prow[256];

  const float* w1e = w1 + (size_t)e * HD * ID;
  const float* w3e = w3 + (size_t)e * HD * ID;

  for (int r0 = 0; r0 < count; r0 += 256) {
    __syncthreads();   // protect pw/prow vs previous epilogue readers
    {
      int idx = r0 + tid;
      bool valid = idx < count;
      prow[tid] = valid ? (pairTok[base + idx] >> 2) : -1;
      pw[tid]   = valid ? pairW[base + idx] : 0.f;
    }
    f32x4 zz = {0.f, 0.f, 0.f, 0.f};
    f32x4 accg[4][4], accu[4][4];
#pragma unroll
    for (int a = 0; a < 4; ++a)
#pragma unroll
      for (int b = 0; b < 4; ++b) { accg[a][b] = zz; accu[a][b] = zz; }

    for (int kk = 0; kk < HD; kk += 32) {
      // ---- stage X tile: thread t = row t, 64 B of bf16 (gather by token)
      {
        int tok = prow[tid];
        u16x8 d0 = {0,0,0,0,0,0,0,0}, d1 = d0, d2 = d0, d3 = d0;
        if (tok >= 0) {
          const u16t* src = xb + (size_t)tok * HD + kk;
          d0 = *(const u16x8*)(src);
          d1 = *(const u16x8*)(src + 8);
          d2 = *(const u16x8*)(src + 16);
          d3 = *(const u16x8*)(src + 24);
        }
        *(u16x8*)&Xs[swz(tid, 0)] = d0;
        *(u16x8*)&Xs[swz(tid, 1)] = d1;
        *(u16x8*)&Xs[swz(tid, 2)] = d2;
        *(u16x8*)&Xs[swz(tid, 3)] = d3;
      }
      // ---- stage W1/W3 tile: 128 threads each; f32 load, bf16 cvt,
      //      transpose-on-store into [col][k]
      {
        const float* wp = (tid < 128) ? w1e : w3e;
        u16t* wsp = &Ws2[tid >> 7][0];
        int u = tid & 127;
        int cg = u & 15, hg = u >> 4;       // 4 cols, 4 h-rows per thread
        const float* src = wp + (size_t)(kk + hg * 4) * ID + colbase + cg * 4;
        fvec4 v0 = *(const fvec4*)(src);
        fvec4 v1 = *(const fvec4*)(src + ID);
        fvec4 v2 = *(const fvec4*)(src + 2 * ID);
        fvec4 v3 = *(const fvec4*)(src + 3 * ID);
        int kc = hg >> 1, half = (hg & 1) * 4;
#pragma unroll
        for (int c = 0; c < 4; ++c) {
          int col = cg * 4 + c;
          u16x4 pk = { f2b(v0[c]), f2b(v1[c]), f2b(v2[c]), f2b(v3[c]) };
          *(u16x4*)&wsp[swz(col, kc) + half] = pk;
        }
      }
      __syncthreads();
      // ---- fragments + MFMA
      bf16x8 af[4], b1f[4], b3f[4];
      int kcl = lane >> 4;
      int rb = wv * 64 + (lane & 15);
#pragma unroll
      for (int rf = 0; rf < 4; ++rf)
        af[rf] = *(const bf16x8*)&Xs[swz(rb + rf * 16, kcl)];
#pragma unroll
      for (int cf = 0; cf < 4; ++cf) {
        int col = cf * 16 + (lane & 15);
        b1f[cf] = *(const bf16x8*)&Ws2[0][swz(col, kcl)];
        b3f[cf] = *(const bf16x8*)&Ws2[1][swz(col, kcl)];
      }
#pragma unroll
      for (int rf = 0; rf < 4; ++rf)
#pragma unroll
        for (int cf = 0; cf < 4; ++cf) {
          accg[rf][cf] = __builtin_amdgcn_mfma_f32_16x16x32_bf16(af[rf], b1f[cf], accg[rf][cf], 0, 0, 0);
          accu[rf][cf] = __builtin_amdgcn_mfma_f32_16x16x32_bf16(af[rf], b3f[cf], accu[rf][cf], 0, 0, 0);
        }
      __syncthreads();
    }
    // ---- epilogue: a = silu(g)*u*routing_w  -> A (bf16)
#pragma unroll
    for (int rf = 0; rf < 4; ++rf) {
#pragma unroll
      for (int ri = 0; ri < 4; ++ri) {
        int rowl = wv * 64 + rf * 16 + (lane >> 4) * 4 + ri;
        int grow = r0 + rowl;
        if (grow < count) {
          float wgt = pw[rowl];
#pragma unroll
          for (int cf = 0; cf < 4; ++cf) {
            float gg = accg[rf][cf][ri];
            float uu = accu[rf][cf][ri];
            float a = gg / (1.f + expf(-gg)) * uu * wgt;
            A[(size_t)(base + grow) * ID + colbase + cf * 16 + (lane & 15)] = f2b(a);
          }
        }
      }
    }
  }
}

// --------------------------------------------------------------- k_gemm2 ---
// Per (expert, 64-wide col tile of H): buf[pair] = A[pair] @ w2[e]
__launch_bounds__(256, 2)
__global__ void k_gemm2(const u16t* __restrict__ A, const float* __restrict__ w2,
                        const int* __restrict__ counts, const int* __restrict__ offsets,
                        float* __restrict__ buf) {
  const int e = blockIdx.y;
  const int colbase = blockIdx.x * 64;
  const int count = counts[e];
  const int base  = offsets[e];
  const int tid = threadIdx.x, lane = tid & 63, wv = tid >> 6;

  __shared__ __align__(16) u16t As[256 * 32];
  __shared__ __align__(16) u16t W2s[64 * 32];

  const float* w2e = w2 + (size_t)e * ID * HD;

  for (int r0 = 0; r0 < count; r0 += 256) {
    f32x4 zz = {0.f, 0.f, 0.f, 0.f};
    f32x4 acc[4][4];
#pragma unroll
    for (int a = 0; a < 4; ++a)
#pragma unroll
      for (int b = 0; b < 4; ++b) acc[a][b] = zz;

    for (int kk = 0; kk < ID; kk += 32) {
      // ---- stage A rows (bucket-contiguous)
      {
        int idx = r0 + tid;
        u16x8 d0 = {0,0,0,0,0,0,0,0}, d1 = d0, d2 = d0, d3 = d0;
        if (idx < count) {
          const u16t* src = A + (size_t)(base + idx) * ID + kk;
          d0 = *(const u16x8*)(src);
          d1 = *(const u16x8*)(src + 8);
          d2 = *(const u16x8*)(src + 16);
          d3 = *(const u16x8*)(src + 24);
        }
        *(u16x8*)&As[swz(tid, 0)] = d0;
        *(u16x8*)&As[swz(tid, 1)] = d1;
        *(u16x8*)&As[swz(tid, 2)] = d2;
        *(u16x8*)&As[swz(tid, 3)] = d3;
      }
      // ---- stage W2 tile: [col=h][k=i] transposed-on-store
      {
        int cg = tid & 15, kg = tid >> 4;     // 4 cols, 2 k-rows per thread
        const float* src = w2e + (size_t)(kk + kg * 2) * HD + colbase + cg * 4;
        fvec4 v0 = *(const fvec4*)(src);
        fvec4 v1 = *(const fvec4*)(src + HD);
        int k0 = kg * 2;
        int kc = k0 >> 3, off = k0 & 7;
#pragma unroll
        for (int c = 0; c < 4; ++c) {
          int col = cg * 4 + c;
          u32t pk = (u32t)f2b(v0[c]) | ((u32t)f2b(v1[c]) << 16);
          *(u32t*)&W2s[swz(col, kc) + off] = pk;
        }
      }
      __syncthreads();
      bf16x8 af[4], bf[4];
      int kcl = lane >> 4;
      int rb = wv * 64 + (lane & 15);
#pragma unroll
      for (int rf = 0; rf < 4; ++rf)
        af[rf] = *(const bf16x8*)&As[swz(rb + rf * 16, kcl)];
#pragma unroll
      for (int cf = 0; cf < 4; ++cf)
        bf[cf] = *(const bf16x8*)&W2s[swz(cf * 16 + (lane & 15), kcl)];
#pragma unroll
      for (int rf = 0; rf < 4; ++rf)
#pragma unroll
        for (int cf = 0; cf < 4; ++cf)
          acc[rf][cf] = __builtin_amdgcn_mfma_f32_16x16x32_bf16(af[rf], bf[cf], acc[rf][cf], 0, 0, 0);
      __syncthreads();
    }
#pragma unroll
    for (int rf = 0; rf < 4; ++rf)
#pragma unroll
      for (int ri = 0; ri < 4; ++ri) {
        int rowl = wv * 64 + rf * 16 + (lane >> 4) * 4 + ri;
        int grow = r0 + rowl;
        if (grow < count) {
#pragma unroll
          for (int cf = 0; cf < 4; ++cf)
            buf[(size_t)(base + grow) * HD + colbase + cf * 16 + (lane & 15)] = acc[rf][cf][ri];
        }
      }
  }
}

// -------------------------------------------------------------- k_reduce ---
// out[t] = sum over the token's 4 pair partials, fixed k order (deterministic)
__global__ void k_reduce(const float* __restrict__ buf, const int* __restrict__ invp,
                         float* __restrict__ out) {
  int t = blockIdx.x;
  int col = threadIdx.x * 4;
  int p0 = invp[t * 4 + 0], p1 = invp[t * 4 + 1];
  int p2 = invp[t * 4 + 2], p3 = invp[t * 4 + 3];
  fvec4 s = *(const fvec4*)(buf + (size_t)p0 * HD + col);
  s += *(const fvec4*)(buf + (size_t)p1 * HD + col);
  s += *(const fvec4*)(buf + (size_t)p2 * HD + col);
  s += *(const fvec4*)(buf + (size_t)p3 * HD + col);
  *(fvec4*)(out + (size_t)t * HD + col) = s;
}

// ------------------------------------------------------------------ host ---
extern "C" void kernel_launch(void* const* d_in, const int* in_sizes, int n_in,
                              void* d_out, int out_size, void* d_ws, size_t ws_size,
                              hipStream_t stream) {
  const float* x  = (const float*)d_in[0];
  const float* gw = (const float*)d_in[1];
  const float* w1 = (const float*)d_in[2];
  const float* w3 = (const float*)d_in[3];
  const float* w2 = (const float*)d_in[4];
  const float* eb = (const float*)d_in[5];
  float* out = (float*)d_out;

  // Workspace layout (total ~48.3 MB)
  char* ws = (char*)d_ws;
  int*   counts   = (int*)(ws);               // [32]   (zeroed)
  int*   offsets  = (int*)(ws + 256);         // [33]
  int*   topk_ids = (int*)(ws + 4096);        // [8192]
  float* topk_w   = (float*)(ws + 36864);     // [8192]
  int*   pairTok  = (int*)(ws + 69632);       // [8192]
  float* pairW    = (float*)(ws + 102400);    // [8192]
  int*   invp     = (int*)(ws + 135168);      // [8192]
  u16t*  xb       = (u16t*)(ws + 262144);                 // [2048*1024] bf16
  u16t*  Abuf     = (u16t*)(ws + 262144 + 4194304);       // [8192*768]  bf16
  float* buf      = (float*)(ws + 262144 + 4194304 + 12582912); // [8192*1024] f32

  hipMemsetAsync(counts, 0, 4096, stream);
  k_cvt   <<<2048, 256, 0, stream>>>(x, xb);
  k_router<<<512, 256, 0, stream>>>(x, gw, eb, topk_ids, topk_w, counts);
  k_bucket<<<1, 256, 0, stream>>>(topk_ids, topk_w, counts, offsets, pairTok, pairW, invp);
  k_gemm1 <<<dim3(12, 32), 256, 0, stream>>>(xb, w1, w3, counts, offsets, pairTok, pairW, Abuf);
  k_gemm2 <<<dim3(16, 32), 256, 0, stream>>>(Abuf, w2, counts, offsets, buf);
  k_reduce<<<2048, 256, 0, stream>>>(buf, invp, out);
}

// Round 2
// 241.539 us; speedup vs baseline: 1.1371x; 1.1371x over previous
//
#include <hip/hip_runtime.h>
#include <cstdint>

// Problem constants (match reference)
#define TOK 2048
#define HD  1024
#define ID  768
#define NE  32
#define RT  4     // row-tile grid depth (stride loop handles overflow)

typedef unsigned short u16t;
typedef unsigned int   u32t;
typedef __bf16 bf16x8 __attribute__((ext_vector_type(8)));
typedef float  f32x4  __attribute__((ext_vector_type(4)));
typedef u16t   u16x8  __attribute__((ext_vector_type(8)));
typedef u16t   u16x4  __attribute__((ext_vector_type(4)));
typedef float  fvec4  __attribute__((ext_vector_type(4)));

// f32 -> bf16 round-to-nearest-even
__device__ __forceinline__ u16t f2b(float f) {
  u32t u = __float_as_uint(f);
  u32t r = u + 0x7fffu + ((u >> 16) & 1u);
  return (u16t)(r >> 16);
}

// LDS granule swizzle: granule = 8 bf16 (16B). Layout [row][4 granules of k].
// XOR k-chunk with (row>>2)&3; same helper for write and read.
__device__ __forceinline__ int swz(int row, int kc) {
  return (row * 4 + (kc ^ ((row >> 2) & 3))) * 8;   // index in u16 units
}

// ---------------------------------------------------------------- k_cvt ----
__global__ void k_cvt(const float* __restrict__ x, u16t* __restrict__ xb) {
  int i = (blockIdx.x * 256 + threadIdx.x) * 4;
  fvec4 v = *(const fvec4*)(x + i);
  u16x4 o = { f2b(v[0]), f2b(v[1]), f2b(v[2]), f2b(v[3]) };
  *(u16x4*)(xb + i) = o;
}

// -------------------------------------------------------------- k_router ---
// 1 wave per token; x row cached in 16 VGPRs; vec4 loads of gate weights.
__global__ void k_router(const float* __restrict__ x, const float* __restrict__ gw,
                         const float* __restrict__ eb,
                         int* __restrict__ topk_ids, float* __restrict__ topk_w,
                         int* __restrict__ counts) {
  int lane = threadIdx.x & 63;
  int t = blockIdx.x * 4 + (threadIdx.x >> 6);
  const float* xt = x + (size_t)t * HD;
  fvec4 xr[4];
#pragma unroll
  for (int i = 0; i < 4; ++i) xr[i] = *(const fvec4*)(xt + lane * 4 + i * 256);
  float myscore = 0.f;
  for (int e = 0; e < NE; ++e) {
    const float* ge = gw + (size_t)e * HD + lane * 4;
    float s = 0.f;
#pragma unroll
    for (int i = 0; i < 4; ++i) {
      fvec4 g = *(const fvec4*)(ge + i * 256);
      s = fmaf(xr[i][0], g[0], s); s = fmaf(xr[i][1], g[1], s);
      s = fmaf(xr[i][2], g[2], s); s = fmaf(xr[i][3], g[3], s);
    }
#pragma unroll
    for (int off = 32; off; off >>= 1) s += __shfl_xor(s, off);
    if (lane == e) myscore = s;
  }
  float sig = 1.f / (1.f + expf(-myscore));
  float biased = (lane < NE) ? (sig + eb[lane]) : -3.0e38f;
  float wsum = 0.f;
  int ids[4]; float wsv[4];
#pragma unroll
  for (int k = 0; k < 4; ++k) {
    float v = biased; int idx = lane;
#pragma unroll
    for (int off = 32; off; off >>= 1) {
      float ov = __shfl_xor(v, off);
      int   oi = __shfl_xor(idx, off);
      if (ov > v || (ov == v && oi < idx)) { v = ov; idx = oi; }
    }
    ids[k] = idx;
    float sc = __shfl(sig, idx);   // uncorrected sigmoid score is the weight
    wsv[k] = sc; wsum += sc;
    if (lane == idx) biased = -3.0e38f;
  }
  float inv = 1.f / wsum;
#pragma unroll
  for (int k = 0; k < 4; ++k) {
    if (lane == k) {
      topk_ids[t * 4 + k] = ids[k];
      topk_w[t * 4 + k]  = wsv[k] * inv;
      atomicAdd(&counts[ids[k]], 1);
    }
  }
}

// -------------------------------------------------------------- k_bucket ---
__global__ void k_bucket(const int* __restrict__ topk_ids, const float* __restrict__ topk_w,
                         const int* __restrict__ counts, int* __restrict__ offsets,
                         int* __restrict__ pairTok, float* __restrict__ pairW,
                         int* __restrict__ invp) {
  __shared__ int soff[NE + 1];
  __shared__ int scur[NE];
  int tid = threadIdx.x;
  if (tid == 0) {
    int acc = 0;
    for (int e = 0; e < NE; ++e) { soff[e] = acc; acc += counts[e]; }
    soff[NE] = acc;
  }
  if (tid < NE) scur[tid] = 0;
  __syncthreads();
  if (tid <= NE) offsets[tid] = soff[tid];
  for (int p = tid; p < TOK * 4; p += 256) {
    int e = topk_ids[p];
    int pos = soff[e] + atomicAdd(&scur[e], 1);
    pairTok[pos] = p;          // p = t*4+k
    pairW[pos]   = topk_w[p];
    invp[p]      = pos;
  }
}

// --------------------------------------------------------------- k_gemm1 ---
// grid (12 col-tiles, 32 experts, RT row-tiles); 256x64 tile, BK=32,
// 2-phase register-prefetch pipeline (T3/T14): issue k+1 loads before MFMA(k).
__launch_bounds__(256, 2)
__global__ void k_gemm1(const u16t* __restrict__ xb, const float* __restrict__ w1,
                        const float* __restrict__ w3,
                        const int* __restrict__ counts, const int* __restrict__ offsets,
                        const int* __restrict__ pairTok, const float* __restrict__ pairW,
                        u16t* __restrict__ A) {
  const int e = blockIdx.y;
  const int colbase = blockIdx.x * 64;
  const int count = counts[e];
  const int base  = offsets[e];
  const int tid = threadIdx.x, lane = tid & 63, wv = tid >> 6;

  __shared__ __align__(16) u16t Xs[256 * 32];     // 16 KB, swizzled [row][k]
  __shared__ __align__(16) u16t Ws2[2][64 * 32];  // w1/w3 tiles, [col][k] swizzled
  __shared__ float pw[256];

  const float* wp = (tid < 128) ? (w1 + (size_t)e * HD * ID)
                                : (w3 + (size_t)e * HD * ID);
  u16t* wsp = &Ws2[tid >> 7][0];
  const int u  = tid & 127;
  const int cg = u & 15, hg = u >> 4;       // 4 cols, 4 h-rows per thread
  const int kc = hg >> 1, half = (hg & 1) * 4;

  for (int r0 = blockIdx.z * 256; r0 < count; r0 += RT * 256) {
    __syncthreads();   // protect pw vs previous tile's epilogue readers
    int idx = r0 + tid;
    bool valid = idx < count;
    int pr = valid ? (pairTok[base + idx] >> 2) : -1;
    pw[tid] = valid ? pairW[base + idx] : 0.f;

    // staging registers
    u16x8 xd[4];
    fvec4 wd[4];
    // prologue: prefetch kk = 0
    {
      if (pr >= 0) {
        const u16t* s = xb + (size_t)pr * HD;
        xd[0] = *(const u16x8*)(s);      xd[1] = *(const u16x8*)(s + 8);
        xd[2] = *(const u16x8*)(s + 16); xd[3] = *(const u16x8*)(s + 24);
      } else {
        u16x8 z = {0,0,0,0,0,0,0,0};
        xd[0] = z; xd[1] = z; xd[2] = z; xd[3] = z;
      }
      const float* s = wp + (size_t)(hg * 4) * ID + colbase + cg * 4;
      wd[0] = *(const fvec4*)(s);          wd[1] = *(const fvec4*)(s + ID);
      wd[2] = *(const fvec4*)(s + 2 * ID); wd[3] = *(const fvec4*)(s + 3 * ID);
    }

    f32x4 zz = {0.f, 0.f, 0.f, 0.f};
    f32x4 accg[4][4], accu[4][4];
#pragma unroll
    for (int a = 0; a < 4; ++a)
#pragma unroll
      for (int b = 0; b < 4; ++b) { accg[a][b] = zz; accu[a][b] = zz; }

    for (int kk = 0; kk < HD; kk += 32) {
      __syncthreads();   // prev tile's readers done
      // ---- write staged regs -> LDS
      *(u16x8*)&Xs[swz(tid, 0)] = xd[0];
      *(u16x8*)&Xs[swz(tid, 1)] = xd[1];
      *(u16x8*)&Xs[swz(tid, 2)] = xd[2];
      *(u16x8*)&Xs[swz(tid, 3)] = xd[3];
#pragma unroll
      for (int c = 0; c < 4; ++c) {
        u16x4 pk = { f2b(wd[0][c]), f2b(wd[1][c]), f2b(wd[2][c]), f2b(wd[3][c]) };
        *(u16x4*)&wsp[swz(cg * 4 + c, kc) + half] = pk;
      }
      __syncthreads();
      // ---- prefetch kk+32 (overlaps with MFMA phase below)
      if (kk + 32 < HD) {
        if (pr >= 0) {
          const u16t* s = xb + (size_t)pr * HD + kk + 32;
          xd[0] = *(const u16x8*)(s);      xd[1] = *(const u16x8*)(s + 8);
          xd[2] = *(const u16x8*)(s + 16); xd[3] = *(const u16x8*)(s + 24);
        }
        const float* s = wp + (size_t)(kk + 32 + hg * 4) * ID + colbase + cg * 4;
        wd[0] = *(const fvec4*)(s);          wd[1] = *(const fvec4*)(s + ID);
        wd[2] = *(const fvec4*)(s + 2 * ID); wd[3] = *(const fvec4*)(s + 3 * ID);
      }
      // ---- fragments + MFMA
      const int kcl = lane >> 4;
      const int rb = wv * 64 + (lane & 15);
      bf16x8 af[4];
#pragma unroll
      for (int rf = 0; rf < 4; ++rf)
        af[rf] = *(const bf16x8*)&Xs[swz(rb + rf * 16, kcl)];
#pragma unroll
      for (int cf = 0; cf < 4; ++cf) {
        int col = cf * 16 + (lane & 15);
        bf16x8 b1f = *(const bf16x8*)&Ws2[0][swz(col, kcl)];
        bf16x8 b3f = *(const bf16x8*)&Ws2[1][swz(col, kcl)];
#pragma unroll
        for (int rf = 0; rf < 4; ++rf) {
          accg[rf][cf] = __builtin_amdgcn_mfma_f32_16x16x32_bf16(af[rf], b1f, accg[rf][cf], 0, 0, 0);
          accu[rf][cf] = __builtin_amdgcn_mfma_f32_16x16x32_bf16(af[rf], b3f, accu[rf][cf], 0, 0, 0);
        }
      }
    }
    // ---- epilogue: a = silu(g)*u*routing_w  -> A (bf16)
    __syncthreads();   // pw fully written (it was, long ago); keeps pw stable
#pragma unroll
    for (int rf = 0; rf < 4; ++rf) {
#pragma unroll
      for (int ri = 0; ri < 4; ++ri) {
        int rowl = wv * 64 + rf * 16 + (lane >> 4) * 4 + ri;
        int grow = r0 + rowl;
        if (grow < count) {
          float wgt = pw[rowl];
#pragma unroll
          for (int cf = 0; cf < 4; ++cf) {
            float gg = accg[rf][cf][ri];
            float uu = accu[rf][cf][ri];
            float a = gg / (1.f + expf(-gg)) * uu * wgt;
            A[(size_t)(base + grow) * ID + colbase + cf * 16 + (lane & 15)] = f2b(a);
          }
        }
      }
    }
  }
}

// --------------------------------------------------------------- k_gemm2 ---
// grid (16 col-tiles, 32 experts, RT); same 2-phase prefetch pipeline.
__launch_bounds__(256, 2)
__global__ void k_gemm2(const u16t* __restrict__ A, const float* __restrict__ w2,
                        const int* __restrict__ counts, const int* __restrict__ offsets,
                        float* __restrict__ buf) {
  const int e = blockIdx.y;
  const int colbase = blockIdx.x * 64;
  const int count = counts[e];
  const int base  = offsets[e];
  const int tid = threadIdx.x, lane = tid & 63, wv = tid >> 6;

  __shared__ __align__(16) u16t As[256 * 32];
  __shared__ __align__(16) u16t W2s[64 * 32];

  const float* w2e = w2 + (size_t)e * ID * HD;
  const int cg = tid & 15, kg = tid >> 4;     // 4 cols, 2 k-rows per thread
  const int k0 = kg * 2, kcw = k0 >> 3, offw = k0 & 7;

  for (int r0 = blockIdx.z * 256; r0 < count; r0 += RT * 256) {
    int idx = r0 + tid;
    bool valid = idx < count;
    const u16t* asrc = A + (size_t)(base + idx) * ID;

    u16x8 xd[4];
    fvec4 wd0, wd1;
    {
      if (valid) {
        xd[0] = *(const u16x8*)(asrc);      xd[1] = *(const u16x8*)(asrc + 8);
        xd[2] = *(const u16x8*)(asrc + 16); xd[3] = *(const u16x8*)(asrc + 24);
      } else {
        u16x8 z = {0,0,0,0,0,0,0,0};
        xd[0] = z; xd[1] = z; xd[2] = z; xd[3] = z;
      }
      const float* s = w2e + (size_t)(kg * 2) * HD + colbase + cg * 4;
      wd0 = *(const fvec4*)(s); wd1 = *(const fvec4*)(s + HD);
    }

    f32x4 zz = {0.f, 0.f, 0.f, 0.f};
    f32x4 acc[4][4];
#pragma unroll
    for (int a = 0; a < 4; ++a)
#pragma unroll
      for (int b = 0; b < 4; ++b) acc[a][b] = zz;

    for (int kk = 0; kk < ID; kk += 32) {
      __syncthreads();
      *(u16x8*)&As[swz(tid, 0)] = xd[0];
      *(u16x8*)&As[swz(tid, 1)] = xd[1];
      *(u16x8*)&As[swz(tid, 2)] = xd[2];
      *(u16x8*)&As[swz(tid, 3)] = xd[3];
#pragma unroll
      for (int c = 0; c < 4; ++c) {
        u32t pk = (u32t)f2b(wd0[c]) | ((u32t)f2b(wd1[c]) << 16);
        *(u32t*)&W2s[swz(cg * 4 + c, kcw) + offw] = pk;
      }
      __syncthreads();
      if (kk + 32 < ID) {
        if (valid) {
          const u16t* s = asrc + kk + 32;
          xd[0] = *(const u16x8*)(s);      xd[1] = *(const u16x8*)(s + 8);
          xd[2] = *(const u16x8*)(s + 16); xd[3] = *(const u16x8*)(s + 24);
        }
        const float* s = w2e + (size_t)(kk + 32 + kg * 2) * HD + colbase + cg * 4;
        wd0 = *(const fvec4*)(s); wd1 = *(const fvec4*)(s + HD);
      }
      const int kcl = lane >> 4;
      const int rb = wv * 64 + (lane & 15);
      bf16x8 af[4];
#pragma unroll
      for (int rf = 0; rf < 4; ++rf)
        af[rf] = *(const bf16x8*)&As[swz(rb + rf * 16, kcl)];
#pragma unroll
      for (int cf = 0; cf < 4; ++cf) {
        bf16x8 bfr = *(const bf16x8*)&W2s[swz(cf * 16 + (lane & 15), kcl)];
#pragma unroll
        for (int rf = 0; rf < 4; ++rf)
          acc[rf][cf] = __builtin_amdgcn_mfma_f32_16x16x32_bf16(af[rf], bfr, acc[rf][cf], 0, 0, 0);
      }
    }
#pragma unroll
    for (int rf = 0; rf < 4; ++rf)
#pragma unroll
      for (int ri = 0; ri < 4; ++ri) {
        int rowl = wv * 64 + rf * 16 + (lane >> 4) * 4 + ri;
        int grow = r0 + rowl;
        if (grow < count) {
#pragma unroll
          for (int cf = 0; cf < 4; ++cf)
            buf[(size_t)(base + grow) * HD + colbase + cf * 16 + (lane & 15)] = acc[rf][cf][ri];
        }
      }
  }
}

// -------------------------------------------------------------- k_reduce ---
__global__ void k_reduce(const float* __restrict__ buf, const int* __restrict__ invp,
                         float* __restrict__ out) {
  int t = blockIdx.x;
  int col = threadIdx.x * 4;
  int p0 = invp[t * 4 + 0], p1 = invp[t * 4 + 1];
  int p2 = invp[t * 4 + 2], p3 = invp[t * 4 + 3];
  fvec4 s = *(const fvec4*)(buf + (size_t)p0 * HD + col);
  s += *(const fvec4*)(buf + (size_t)p1 * HD + col);
  s += *(const fvec4*)(buf + (size_t)p2 * HD + col);
  s += *(const fvec4*)(buf + (size_t)p3 * HD + col);
  *(fvec4*)(out + (size_t)t * HD + col) = s;
}

// ------------------------------------------------------------------ host ---
extern "C" void kernel_launch(void* const* d_in, const int* in_sizes, int n_in,
                              void* d_out, int out_size, void* d_ws, size_t ws_size,
                              hipStream_t stream) {
  const float* x  = (const float*)d_in[0];
  const float* gw = (const float*)d_in[1];
  const float* w1 = (const float*)d_in[2];
  const float* w3 = (const float*)d_in[3];
  const float* w2 = (const float*)d_in[4];
  const float* eb = (const float*)d_in[5];
  float* out = (float*)d_out;

  char* ws = (char*)d_ws;
  int*   counts   = (int*)(ws);               // [32]   (zeroed)
  int*   offsets  = (int*)(ws + 256);         // [33]
  int*   topk_ids = (int*)(ws + 4096);        // [8192]
  float* topk_w   = (float*)(ws + 36864);     // [8192]
  int*   pairTok  = (int*)(ws + 69632);       // [8192]
  float* pairW    = (float*)(ws + 102400);    // [8192]
  int*   invp     = (int*)(ws + 135168);      // [8192]
  u16t*  xb       = (u16t*)(ws + 262144);                 // [2048*1024] bf16
  u16t*  Abuf     = (u16t*)(ws + 262144 + 4194304);       // [8192*768]  bf16
  float* buf      = (float*)(ws + 262144 + 4194304 + 12582912); // [8192*1024] f32

  hipMemsetAsync(counts, 0, 4096, stream);
  k_cvt   <<<2048, 256, 0, stream>>>(x, xb);
  k_router<<<512, 256, 0, stream>>>(x, gw, eb, topk_ids, topk_w, counts);
  k_bucket<<<1, 256, 0, stream>>>(topk_ids, topk_w, counts, offsets, pairTok, pairW, invp);
  k_gemm1 <<<dim3(12, 32, RT), 256, 0, stream>>>(xb, w1, w3, counts, offsets, pairTok, pairW, Abuf);
  k_gemm2 <<<dim3(16, 32, RT), 256, 0, stream>>>(Abuf, w2, counts, offsets, buf);
  k_reduce<<<2048, 256, 0, stream>>>(buf, invp, out);
}